// Round 9
// baseline (136.597 us; speedup 1.0000x reference)
//
#include <hip/hip_runtime.h>

// SpatioTemporalGCN: B=64, T=12, N=1024, Ci=64, E=16, K=3, H=192, O=64
// out(b,n,:) = [l2norm(gconv) | l2norm(aconv) | l2norm(wconv)] + bias(n,:)
//
// r9 = r8 + k_epi bulk-staged via global_load_lds (Wall 32KB + Y1/Y2 16KB per block).
// Y1/Y2 stored in fragment layout [n][j>>3][b][j&7] so the DMA is linear.

typedef __attribute__((ext_vector_type(4))) float f32x4;
typedef __attribute__((ext_vector_type(8))) short short8;

#define DEVI static __device__ __forceinline__

DEVI short f2bf(float f) {
    unsigned int x = __builtin_bit_cast(unsigned int, f);
    x = (x + 0x7FFFu + ((x >> 16) & 1u)) >> 16;  // RNE
    return (short)(unsigned short)x;
}
DEVI int swz(int row) { return ((row ^ (row >> 3)) & 7) << 3; }

DEVI f32x4 mfma16(short8 a, short8 b, f32x4 c) {
    return __builtin_amdgcn_mfma_f32_16x16x32_bf16(a, b, c, 0, 0, 0);
}

DEVI void gload16(const void* g, void* l) {
    __builtin_amdgcn_global_load_lds(
        (const __attribute__((address_space(1))) unsigned int*)g,
        (__attribute__((address_space(3))) unsigned int*)l, 16, 0, 0);
}

// ---------------- supports: S = softmax(relu(E E^T), axis=1), bf16 row-major ----------------
__global__ __launch_bounds__(256) void k_supports(const float* __restrict__ NE,
                                                  short* __restrict__ S) {
    int n = blockIdx.x, t = threadIdx.x;
    __shared__ float En[16];
    __shared__ float wsum[4];
    if (t < 16) En[t] = NE[n * 16 + t];
    __syncthreads();
    float e[4];
    float loc = 0.f;
#pragma unroll
    for (int i = 0; i < 4; ++i) {
        int m = t + 256 * i;
        const float* rp = NE + m * 16;
        float v = 0.f;
#pragma unroll
        for (int d = 0; d < 16; ++d) v += En[d] * rp[d];
        v = fmaxf(v, 0.f);
        e[i] = __expf(v);
        loc += e[i];
    }
#pragma unroll
    for (int off = 32; off; off >>= 1) loc += __shfl_xor(loc, off);
    if ((t & 63) == 0) wsum[t >> 6] = loc;
    __syncthreads();
    float inv = 1.f / (wsum[0] + wsum[1] + wsum[2] + wsum[3]);
#pragma unroll
    for (int i = 0; i < 4; ++i) S[n * 1024 + t + 256 * i] = f2bf(e[i] * inv);
}

// ---------------- misc prep: B2 rows, xsum partials, s_bn, A2 rows ----------------
__global__ __launch_bounds__(256) void k_small(
        const float* __restrict__ x, const float* __restrict__ xw,
        const float* __restrict__ NE, const float* __restrict__ adj,
        const float* __restrict__ wp, const float* __restrict__ wpa,
        const float* __restrict__ Tp,
        short* __restrict__ B2, short* __restrict__ A2,
        float* __restrict__ xsp, float* __restrict__ s_bn) {
    __shared__ float red[4][64];
    int bid = blockIdx.x, t = threadIdx.x;
    if (bid < 64) {  // B2 operand rows for o = bid
        int o = bid, j = t;
        short row[64];
        if (j < 192) {
            int kk = j >> 6, i = j & 63;
#pragma unroll
            for (int d = 0; d < 16; ++d)
                row[d] = f2bf(wp[((d * 3 + kk) * 64 + i) * 64 + o]);
#pragma unroll
            for (int k = 16; k < 64; ++k) row[k] = 0;
        } else {
            int i2 = j - 192;
#pragma unroll
            for (int k = 0; k < 16; ++k) row[k] = 0;
#pragma unroll
            for (int d = 0; d < 16; ++d)
#pragma unroll
                for (int kk = 0; kk < 3; ++kk)
                    row[16 + d * 3 + kk] = f2bf(wpa[((d * 3 + kk) * 64 + i2) * 64 + o]);
        }
        short* dst = B2 + (o * 256 + j) * 64;
#pragma unroll
        for (int q = 0; q < 8; ++q) {
            short8 v;
#pragma unroll
            for (int e2 = 0; e2 < 8; ++e2) v[e2] = row[q * 8 + e2];
            *reinterpret_cast<short8*>(dst + q * 8) = v;
        }
    } else if (bid < 320) {  // xsum partials: xsp[(b*4+mq)*64+c]
        int idx = bid - 64, b = idx >> 2, mq = idx & 3;
        int c = t & 63, q2 = t >> 6;
        int m0 = mq * 256 + q2 * 64;
        float s = 0.f;
        for (int mm = 0; mm < 64; ++mm) s += x[((size_t)b * 1024 + m0 + mm) * 64 + c];
        red[q2][c] = s;
        __syncthreads();
        if (t < 64) xsp[(b * 4 + mq) * 64 + t] = red[0][t] + red[1][t] + red[2][t] + red[3][t];
    } else if (bid < 336) {  // s_bn[b][n] = sum_t xw[b,t,n]*Tp[t]
        int idx = bid - 320;
        float tp[12];
#pragma unroll
        for (int i = 0; i < 12; ++i) tp[i] = Tp[i];
        for (int bb = 0; bb < 4; ++bb) {
            int b = idx * 4 + bb;
#pragma unroll
            for (int j2 = 0; j2 < 4; ++j2) {
                int nn = t + 256 * j2;
                float s = 0.f;
#pragma unroll
                for (int tt = 0; tt < 12; ++tt) s += xw[(b * 12 + tt) * 1024 + nn] * tp[tt];
                s_bn[b * 1024 + nn] = s;
            }
        }
    } else {  // A2 rows
        int n = (bid - 336) * 256 + t;
        float En[16];
#pragma unroll
        for (int d = 0; d < 16; ++d) En[d] = NE[n * 16 + d];
        float dg[3];
#pragma unroll
        for (int k = 0; k < 3; ++k) dg[k] = adj[k * 1024 * 1024 + n * 1024 + n];
        short row[64];
#pragma unroll
        for (int d = 0; d < 16; ++d) row[d] = f2bf(En[d]);
#pragma unroll
        for (int d = 0; d < 16; ++d)
#pragma unroll
            for (int k = 0; k < 3; ++k) row[16 + d * 3 + k] = f2bf(En[d] * dg[k]);
        short* dst = A2 + n * 64;
#pragma unroll
        for (int q = 0; q < 8; ++q) {
            short8 v;
#pragma unroll
            for (int e2 = 0; e2 < 8; ++e2) v[e2] = row[q * 8 + e2];
            *reinterpret_cast<short8*>(dst + q * 8) = v;
        }
    }
}

// ---------------- gemm1: y1 = S @ x[b] -> Y1F frag layout [n][c>>3][b][c&7] ----------------
__global__ __launch_bounds__(256) void k_gemm1(const short* __restrict__ S,
                                               const float* __restrict__ x,
                                               short* __restrict__ Y1F) {
    __shared__ __align__(16) short As[128 * 64];
    __shared__ __align__(16) short Bs[64 * 64];
    int bx = blockIdx.x, b = blockIdx.y, t = threadIdx.x;
    int wid = t >> 6, lane = t & 63;
    int rsub = lane >> 3, csub = (lane & 7) * 8;
    int wm = wid & 1, wn = wid >> 1;
    int lr = lane & 15, lg = lane >> 4;
    const short* A = S + (size_t)bx * 131072;
    const float* xb = x + (size_t)b * 65536;
    int bm = t >> 2, bc = (t & 3) * 16;
    f32x4 acc[4][2] = {};
    for (int kt = 0; kt < 16; ++kt) {
#pragma unroll
        for (int q = 0; q < 4; ++q) {
            int row = q * 32 + wid * 8;
            gload16(A + (size_t)(row + rsub) * 1024 + kt * 64 + csub, As + row * 64);
        }
#pragma unroll
        for (int j = 0; j < 4; ++j) {
            float4 f = *reinterpret_cast<const float4*>(&xb[(kt * 64 + bm) * 64 + bc + 4 * j]);
            float vv[4] = {f.x, f.y, f.z, f.w};
#pragma unroll
            for (int e = 0; e < 4; ++e) {
                int c = bc + 4 * j + e;
                Bs[c * 64 + (bm ^ swz(c))] = f2bf(vv[e]);
            }
        }
        __syncthreads();
#pragma unroll
        for (int ks = 0; ks < 2; ++ks) {
            int kk = ks * 32 + lg * 8;
            short8 af[4], bfr[2];
#pragma unroll
            for (int i = 0; i < 4; ++i)
                af[i] = *reinterpret_cast<const short8*>(&As[(wm * 64 + i * 16 + lr) * 64 + kk]);
#pragma unroll
            for (int nf = 0; nf < 2; ++nf) {
                int c = wn * 32 + nf * 16 + lr;
                bfr[nf] = *reinterpret_cast<const short8*>(&Bs[c * 64 + (kk ^ swz(c))]);
            }
#pragma unroll
            for (int i = 0; i < 4; ++i)
#pragma unroll
                for (int nf = 0; nf < 2; ++nf)
                    acc[i][nf] = mfma16(af[i], bfr[nf], acc[i][nf]);
        }
        __syncthreads();
    }
#pragma unroll
    for (int i = 0; i < 4; ++i)
#pragma unroll
        for (int nf = 0; nf < 2; ++nf)
#pragma unroll
            for (int r = 0; r < 4; ++r) {
                int g = wm * 64 + i * 16 + lg * 4 + r;
                int c = wn * 32 + nf * 16 + lr;
                Y1F[(size_t)(bx * 128 + g) * 4096 + (size_t)(c >> 3) * 512 + b * 8 + (c & 7)] =
                    f2bf(acc[i][nf][r]);
            }
}

// ---------------- gemm2: y2 = S @ y1[b] (B from Y1F frag) -> Y2F frag ----------------
__global__ __launch_bounds__(256) void k_gemm2(const short* __restrict__ S,
                                               const short* __restrict__ Y1F,
                                               short* __restrict__ Y2F) {
    __shared__ __align__(16) short As[128 * 64];
    __shared__ __align__(16) short Bs[64 * 64];
    int bx = blockIdx.x, b = blockIdx.y, t = threadIdx.x;
    int wid = t >> 6, lane = t & 63;
    int rsub = lane >> 3, csub = (lane & 7) * 8;
    int wm = wid & 1, wn = wid >> 1;
    int lr = lane & 15, lg = lane >> 4;
    const short* A = S + (size_t)bx * 131072;
    int bm = t >> 3, q0 = t & 7;
    f32x4 acc[4][2] = {};
    for (int kt = 0; kt < 16; ++kt) {
#pragma unroll
        for (int q = 0; q < 4; ++q) {
            int row = q * 32 + wid * 8;
            gload16(A + (size_t)(row + rsub) * 1024 + kt * 64 + csub, As + row * 64);
        }
#pragma unroll
        for (int it = 0; it < 2; ++it) {
            int m = bm + 32 * it;
            short8 hv = *reinterpret_cast<const short8*>(
                &Y1F[(size_t)(kt * 64 + m) * 4096 + (size_t)q0 * 512 + b * 8]);
#pragma unroll
            for (int j = 0; j < 8; ++j) {
                int c = q0 * 8 + j;
                Bs[c * 64 + (m ^ swz(c))] = hv[j];
            }
        }
        __syncthreads();
#pragma unroll
        for (int ks = 0; ks < 2; ++ks) {
            int kk = ks * 32 + lg * 8;
            short8 af[4], bfr[2];
#pragma unroll
            for (int i = 0; i < 4; ++i)
                af[i] = *reinterpret_cast<const short8*>(&As[(wm * 64 + i * 16 + lr) * 64 + kk]);
#pragma unroll
            for (int nf = 0; nf < 2; ++nf) {
                int c = wn * 32 + nf * 16 + lr;
                bfr[nf] = *reinterpret_cast<const short8*>(&Bs[c * 64 + (kk ^ swz(c))]);
            }
#pragma unroll
            for (int i = 0; i < 4; ++i)
#pragma unroll
                for (int nf = 0; nf < 2; ++nf)
                    acc[i][nf] = mfma16(af[i], bfr[nf], acc[i][nf]);
        }
        __syncthreads();
    }
#pragma unroll
    for (int i = 0; i < 4; ++i)
#pragma unroll
        for (int nf = 0; nf < 2; ++nf)
#pragma unroll
            for (int r = 0; r < 4; ++r) {
                int g = wm * 64 + i * 16 + lg * 4 + r;
                int c = wn * 32 + nf * 16 + lr;
                Y2F[(size_t)(bx * 128 + g) * 4096 + (size_t)(c >> 3) * 512 + b * 8 + (c & 7)] =
                    f2bf(acc[i][nf][r]);
            }
}

// ---------------- Wall = A2 @ B2^T, fragment-interleaved; spare blocks: xsF finalize ----------------
// Wall[n*16384 + (j>>3)*512 + o*8 + (j&7)]; xsF[(c>>3)*512 + b*8 + (c&7)]
__global__ __launch_bounds__(256) void k_gemm_w(const short* __restrict__ A2,
                                                const short* __restrict__ B2,
                                                short* __restrict__ Wall,
                                                const float* __restrict__ xsp,
                                                short* __restrict__ xsF) {
    int bx = blockIdx.x, by = blockIdx.y, t = threadIdx.x;
    if (bx == 128) {  // xsF finalize: 8 blocks x 512 = 4096 outputs
#pragma unroll
        for (int p = 0; p < 2; ++p) {
            int j = by * 512 + p * 256 + t;
            int b = j >> 6, c = j & 63;
            float s = xsp[(b * 4 + 0) * 64 + c] + xsp[(b * 4 + 1) * 64 + c] +
                      xsp[(b * 4 + 2) * 64 + c] + xsp[(b * 4 + 3) * 64 + c];
            xsF[(c >> 3) * 512 + b * 8 + (c & 7)] = f2bf(s);
        }
        return;
    }
    __shared__ __align__(16) short As[128 * 64];
    __shared__ __align__(16) short Bs[128 * 64];
#pragma unroll
    for (int i = 0; i < 4; ++i) {
        int slot = t + 256 * i;
        int row = slot >> 3, k8 = slot & 7;
        int sw = swz(row);
        short8 va = *reinterpret_cast<const short8*>(A2 + (by * 128 + row) * 64 + k8 * 8);
        *reinterpret_cast<short8*>(&As[row * 64 + ((k8 * 8) ^ sw)]) = va;
        short8 vb = *reinterpret_cast<const short8*>(B2 + (bx * 128 + row) * 64 + k8 * 8);
        *reinterpret_cast<short8*>(&Bs[row * 64 + ((k8 * 8) ^ sw)]) = vb;
    }
    __syncthreads();
    int w = t >> 6, l = t & 63;
    int wm = w & 1, wn = w >> 1;
    int lr = l & 15, lg = l >> 4;
    f32x4 acc[4][4] = {};
#pragma unroll
    for (int ks = 0; ks < 2; ++ks) {
        int kk = ks * 32 + lg * 8;
        short8 af[4], bfr[4];
#pragma unroll
        for (int mf = 0; mf < 4; ++mf) {
            int row = wm * 64 + mf * 16 + lr;
            af[mf] = *reinterpret_cast<const short8*>(&As[row * 64 + (kk ^ swz(row))]);
        }
#pragma unroll
        for (int nf = 0; nf < 4; ++nf) {
            int row = wn * 64 + nf * 16 + lr;
            bfr[nf] = *reinterpret_cast<const short8*>(&Bs[row * 64 + (kk ^ swz(row))]);
        }
#pragma unroll
        for (int mf = 0; mf < 4; ++mf)
#pragma unroll
            for (int nf = 0; nf < 4; ++nf)
                acc[mf][nf] = mfma16(af[mf], bfr[nf], acc[mf][nf]);
    }
#pragma unroll
    for (int mf = 0; mf < 4; ++mf)
#pragma unroll
        for (int nf = 0; nf < 4; ++nf)
#pragma unroll
            for (int r = 0; r < 4; ++r) {
                int row = by * 128 + wm * 64 + mf * 16 + lg * 4 + r;
                int col = bx * 128 + wn * 64 + nf * 16 + lr;
                int o = col >> 8, j = col & 255;
                Wall[(size_t)row * 16384 + (size_t)(j >> 3) * 512 + o * 8 + (j & 7)] =
                    f2bf(acc[mf][nf][r]);
            }
}

// ---------------- epilogue: LDS-staged per-node MFMA (M=64 b, N=64 o, K=256) ----------------
__global__ __launch_bounds__(256) void k_epi(
        const float* __restrict__ x, const short* __restrict__ Y1F,
        const short* __restrict__ Y2F, const short* __restrict__ xsF,
        const float* __restrict__ s_bn, const short* __restrict__ Wall,
        const float* __restrict__ NE, const float* __restrict__ bp,
        const float* __restrict__ wwin, float* __restrict__ out) {
    int n = blockIdx.x, t = threadIdx.x;
    __shared__ __align__(16) short A_lds[16 * 512];   // 16 KB: Y1 octets 0..7, Y2 8..15
    __shared__ __align__(16) short W_lds[32 * 512];   // 32 KB
    __shared__ float bias_l[192];
    __shared__ float ww_l[64];
    __shared__ float sq_l[2][2][64];
    __shared__ float wwn_l;
    int lane = t & 63, wid = t >> 6;
    // ---- bulk DMA staging (fire-and-forget) ----
#pragma unroll
    for (int r = 0; r < 4; ++r) {  // Y1F+Y2F: 16 chunks of 1KB
        int off = (r * 4 + wid) * 512;
        const short* src = (off < 4096) ? (Y1F + (size_t)n * 4096 + off)
                                        : (Y2F + (size_t)n * 4096 + (off - 4096));
        gload16(src + lane * 8, A_lds + off);
    }
#pragma unroll
    for (int r = 0; r < 8; ++r) {  // Wall: 32 chunks of 1KB
        int off = (r * 4 + wid) * 512;
        gload16(Wall + (size_t)n * 16384 + off + lane * 8, W_lds + off);
    }
    // ---- bias / window weights (overlaps DMA; NE row is one L2 line) ----
    {
        const float* En = NE + n * 16;
        if (t < 192) {
            float s = 0.f;
#pragma unroll
            for (int d = 0; d < 16; ++d) s += En[d] * bp[d * 192 + t];
            bias_l[t] = s;
        } else {
            int o = t - 192;
            float s = 0.f;
#pragma unroll
            for (int d = 0; d < 16; ++d) s += En[d] * wwin[d * 64 + o];
            ww_l[o] = s;
        }
    }
    __syncthreads();  // drains vmcnt(0): LDS tiles + bias_l/ww_l ready
    if (t < 64) {  // ||ww||
        float v = ww_l[t];
        float s2 = v * v;
#pragma unroll
        for (int off = 32; off; off >>= 1) s2 += __shfl_xor(s2, off);
        if (t == 0) wwn_l = sqrtf(s2);
    }
    int wm = wid & 1, wn = wid >> 1;
    int lr = lane & 15, lg = lane >> 4;
    f32x4 accg[2][2] = {};
    f32x4 acca[2][2] = {};
#pragma unroll
    for (int ks = 0; ks < 8; ++ks) {
        short8 af[2];
#pragma unroll
        for (int mf = 0; mf < 2; ++mf) {
            int b = wm * 32 + mf * 16 + lr;
            if (ks < 2) {  // x direct (f32 -> bf16), L3-resident
                int k0 = ks * 32 + lg * 8;
                const float4* p =
                    reinterpret_cast<const float4*>(&x[((size_t)b * 1024 + n) * 64 + k0]);
                float4 p0 = p[0], p1 = p[1];
                short8 v;
                v[0] = f2bf(p0.x); v[1] = f2bf(p0.y); v[2] = f2bf(p0.z); v[3] = f2bf(p0.w);
                v[4] = f2bf(p1.x); v[5] = f2bf(p1.y); v[6] = f2bf(p1.z); v[7] = f2bf(p1.w);
                af[mf] = v;
            } else if (ks < 6) {  // y1/y2 from LDS
                af[mf] = *reinterpret_cast<const short8*>(
                    &A_lds[((ks - 2) * 4 + lg) * 512 + b * 8]);
            } else {  // xs JIT from global frag buffer (L2-broadcast)
                af[mf] = *reinterpret_cast<const short8*>(
                    &xsF[((ks - 6) * 4 + lg) * 512 + b * 8]);
            }
        }
        short8 wfk[2];
#pragma unroll
        for (int nf = 0; nf < 2; ++nf) {
            int o = wn * 32 + nf * 16 + lr;
            wfk[nf] = *reinterpret_cast<const short8*>(
                &W_lds[(ks * 4 + lg) * 512 + o * 8]);
        }
#pragma unroll
        for (int mf = 0; mf < 2; ++mf)
#pragma unroll
            for (int nf = 0; nf < 2; ++nf) {
                if (ks < 6) accg[mf][nf] = mfma16(af[mf], wfk[nf], accg[mf][nf]);
                else        acca[mf][nf] = mfma16(af[mf], wfk[nf], acca[mf][nf]);
            }
    }
#pragma unroll
    for (int mf = 0; mf < 2; ++mf)
#pragma unroll
        for (int r = 0; r < 4; ++r) {
            float sg = accg[mf][0][r] * accg[mf][0][r] + accg[mf][1][r] * accg[mf][1][r];
            float sa = acca[mf][0][r] * acca[mf][0][r] + acca[mf][1][r] * acca[mf][1][r];
#pragma unroll
            for (int off = 1; off < 16; off <<= 1) {
                sg += __shfl_xor(sg, off);
                sa += __shfl_xor(sa, off);
            }
            if (lr == 0) {
                int b = wm * 32 + mf * 16 + lg * 4 + r;
                sq_l[0][wn][b] = sg;
                sq_l[1][wn][b] = sa;
            }
        }
    __syncthreads();
#pragma unroll
    for (int mf = 0; mf < 2; ++mf)
#pragma unroll
        for (int r = 0; r < 4; ++r) {
            int b = wm * 32 + mf * 16 + lg * 4 + r;
            float ig = 1.f / fmaxf(sqrtf(sq_l[0][0][b] + sq_l[0][1][b]), 1e-12f);
            float ia = 1.f / fmaxf(sqrtf(sq_l[1][0][b] + sq_l[1][1][b]), 1e-12f);
            float* po = out + ((size_t)b * 1024 + n) * 192;
#pragma unroll
            for (int nf = 0; nf < 2; ++nf) {
                int o = wn * 32 + nf * 16 + lr;
                po[o]      = accg[mf][nf][r] * ig + bias_l[o];
                po[64 + o] = acca[mf][nf][r] * ia + bias_l[64 + o];
            }
        }
    // wconv
    float wwn = wwn_l;
#pragma unroll
    for (int it = 0; it < 16; ++it) {
        int b = it * 4 + (t >> 6);
        int o = t & 63;
        float s = s_bn[b * 1024 + n];
        float pre = s * ww_l[o];
        float nrm = fabsf(s) * wwn;
        out[((size_t)b * 1024 + n) * 192 + 128 + o] = pre / fmaxf(nrm, 1e-12f) + bias_l[128 + o];
    }
}

extern "C" void kernel_launch(void* const* d_in, const int* in_sizes, int n_in,
                              void* d_out, int out_size, void* d_ws, size_t ws_size,
                              hipStream_t stream) {
    const float* x    = (const float*)d_in[0];
    const float* xw   = (const float*)d_in[1];
    const float* NE   = (const float*)d_in[2];
    const float* adj  = (const float*)d_in[4];
    const float* wp   = (const float*)d_in[5];
    const float* wpa  = (const float*)d_in[6];
    const float* wwin = (const float*)d_in[7];
    const float* bp   = (const float*)d_in[8];
    const float* Tp   = (const float*)d_in[9];
    float* out = (float*)d_out;

    char* ws = (char*)d_ws;
    const size_t OFF_S    = 0;           // 2 MB
    const size_t OFF_Y1   = 2097152;     // 8 MB (Y1F frag)
    const size_t OFF_Y2   = 10485760;    // 8 MB (Y2F frag)
    const size_t OFF_WALL = 18874368;    // 32 MB
    const size_t OFF_A2   = 52428800;    // 128 KB
    const size_t OFF_B2   = 52559872;    // 2 MB
    const size_t OFF_XSP  = 54657024;    // 64 KB
    const size_t OFF_XSBF = 54722560;    // 8 KB (xsF frag)
    const size_t OFF_SBN  = 54730752;    // 256 KB
    const size_t NEED     = 54992896;
    if (ws_size < NEED) return;  // fails validation loudly

    short* S     = (short*)(ws + OFF_S);
    short* Y1F   = (short*)(ws + OFF_Y1);
    short* Y2F   = (short*)(ws + OFF_Y2);
    short* Wall  = (short*)(ws + OFF_WALL);
    short* A2    = (short*)(ws + OFF_A2);
    short* B2    = (short*)(ws + OFF_B2);
    float* xsp   = (float*)(ws + OFF_XSP);
    short* xsF   = (short*)(ws + OFF_XSBF);
    float* s_bn  = (float*)(ws + OFF_SBN);

    k_supports<<<1024, 256, 0, stream>>>(NE, S);
    k_small<<<340, 256, 0, stream>>>(x, xw, NE, adj, wp, wpa, Tp, B2, A2, xsp, s_bn);
    k_gemm1<<<dim3(8, 64), 256, 0, stream>>>(S, x, Y1F);
    k_gemm2<<<dim3(8, 64), 256, 0, stream>>>(S, Y1F, Y2F);
    k_gemm_w<<<dim3(129, 8), 256, 0, stream>>>(A2, B2, Wall, xsp, xsF);
    k_epi<<<1024, 256, 0, stream>>>(x, Y1F, Y2F, xsF, s_bn, Wall, NE, bp, wwin, out);
}